// Round 1
// baseline (1624.756 us; speedup 1.0000x reference)
//
#include <hip/hip_runtime.h>

#define NT 16
#define NB 8
#define ROWS 64
#define MTHREADS 512
#define GPITCH 130

// ---------------- CSR build ----------------

__global__ void k_deg_cnt(const int* __restrict__ row, const float* __restrict__ ew,
                          float* __restrict__ deg, int* __restrict__ cnt, int E) {
  int e = blockIdx.x * blockDim.x + threadIdx.x;
  if (e < E) {
    int r = row[e];
    atomicAdd(&deg[r], ew[e]);
    atomicAdd(&cnt[r], 1);
  }
}

__global__ __launch_bounds__(1024) void k_scan(const int* __restrict__ cnt,
                                               int* __restrict__ start,
                                               int* __restrict__ nxt, int n) {
  __shared__ int wsum[16];
  __shared__ int carry;
  if (threadIdx.x == 0) carry = 0;
  __syncthreads();
  int lane = threadIdx.x & 63;
  int wid = threadIdx.x >> 6;
  for (int base = 0; base < n; base += 1024) {
    int i = base + threadIdx.x;
    int v = (i < n) ? cnt[i] : 0;
    int s = v;
#pragma unroll
    for (int d = 1; d < 64; d <<= 1) {
      int t = __shfl_up(s, d);
      if (lane >= d) s += t;
    }
    if (lane == 63) wsum[wid] = s;
    __syncthreads();
    if (threadIdx.x < 16) {
      int w2 = wsum[threadIdx.x];
#pragma unroll
      for (int d = 1; d < 16; d <<= 1) {
        int t = __shfl_up(w2, d);
        if ((int)threadIdx.x >= d) w2 += t;
      }
      wsum[threadIdx.x] = w2;
    }
    __syncthreads();
    int wofs = (wid > 0) ? wsum[wid - 1] : 0;
    int incl = s + wofs + carry;
    if (i < n) { start[i] = incl - v; nxt[i] = incl - v; }
    __syncthreads();
    if (threadIdx.x == 1023) carry = incl;
    __syncthreads();
  }
  if (threadIdx.x == 0) start[n] = carry;
}

__global__ void k_scatter(const int* __restrict__ row, const int* __restrict__ col,
                          const int* __restrict__ etype, const float* __restrict__ ew,
                          const float* __restrict__ deg, int* __restrict__ nxt,
                          int* __restrict__ epack, float* __restrict__ enw, int E) {
  int e = blockIdx.x * blockDim.x + threadIdx.x;
  if (e < E) {
    int r = row[e];
    float nw = ew[e] / fmaxf(deg[r], 1e-12f);
    int pos = atomicAdd(&nxt[r], 1);
    epack[pos] = (etype[e] << 16) | col[e];
    enw[pos] = nw;
  }
}

// ---------------- basis combine: Wc[t,i,o] = sum_b alpha[t,b]*weight[b,i,o] -----

__global__ void k_wcomb(const float* __restrict__ alpha, const float* __restrict__ weight,
                        float* __restrict__ Wc) {
  int t = blockIdx.x >> 7;
  int i = blockIdx.x & 127;
  int o = threadIdx.x;
  float s = 0.f;
#pragma unroll
  for (int b = 0; b < NB; ++b)
    s += alpha[t * NB + b] * weight[(b * 128 + i) * 128 + o];
  Wc[(t * 128 + i) * 128 + o] = s;
}

// ---------------- fused aggregate + GEMM + LN + self ----------------

__global__ __launch_bounds__(MTHREADS) void k_main(
    const float* __restrict__ x, const int* __restrict__ rstart,
    const int* __restrict__ epack, const float* __restrict__ enw,
    const float* __restrict__ Wc, const float* __restrict__ wself,
    const float* __restrict__ gamma, const float* __restrict__ beta,
    const float* __restrict__ bias, float* __restrict__ out, int N) {
  __shared__ float g[ROWS][GPITCH];
  int tid = threadIdx.x;
  int lane = tid & 63;
  int w = tid >> 6;  // wave 0..7
  int r0 = blockIdx.x * ROWS;

  int lane16 = tid & 15;
  int rpair = tid >> 4;  // 0..31
  int ob = lane16 * 8;
  int ra = rpair * 2, rb = ra + 1;

  float hacc[2][8];
#pragma unroll
  for (int j = 0; j < 2; ++j)
#pragma unroll
    for (int k = 0; k < 8; ++k) hacc[j][k] = 0.f;

  for (int t = 0; t < NT; ++t) {
    __syncthreads();
    for (int k2 = tid; k2 < ROWS * GPITCH; k2 += MTHREADS) ((float*)g)[k2] = 0.f;
    __syncthreads();
    // aggregate g[r][:] = sum over edges of type t into row r of nw * x[col]
    for (int rr = 0; rr < ROWS / 8; ++rr) {
      int rl = w * (ROWS / 8) + rr;
      int rg = r0 + rl;
      if (rg >= N) continue;
      int sb = rstart[rg], se = rstart[rg + 1];
      for (int j = sb; j < se; j += 64) {
        int e = j + lane;
        int pk = (e < se) ? epack[e] : -1;
        float nw = (e < se) ? enw[e] : 0.f;
        unsigned long long bal = __ballot((pk >> 16) == t);
        while (bal) {
          int src = (int)__builtin_ctzll(bal);
          bal &= bal - 1;
          int c = __shfl(pk, src) & 0xFFFF;
          float w_ = __shfl(nw, src);
          float2 xv = *(const float2*)(x + c * 128 + lane * 2);
          float2* gp = (float2*)&g[rl][lane * 2];
          float2 cur = *gp;
          cur.x += w_ * xv.x;
          cur.y += w_ * xv.y;
          *gp = cur;
        }
      }
    }
    __syncthreads();
    // GEMM accumulate: hacc += g @ W_t  (2 rows x 8 cols per thread)
    const float* Wt = Wc + t * (128 * 128);
#pragma unroll 4
    for (int i = 0; i < 128; ++i) {
      float g0 = g[ra][i];
      float g1 = g[rb][i];
      float4 w0 = *(const float4*)(Wt + i * 128 + ob);
      float4 w1 = *(const float4*)(Wt + i * 128 + ob + 4);
      hacc[0][0] += g0 * w0.x; hacc[0][1] += g0 * w0.y;
      hacc[0][2] += g0 * w0.z; hacc[0][3] += g0 * w0.w;
      hacc[0][4] += g0 * w1.x; hacc[0][5] += g0 * w1.y;
      hacc[0][6] += g0 * w1.z; hacc[0][7] += g0 * w1.w;
      hacc[1][0] += g1 * w0.x; hacc[1][1] += g1 * w0.y;
      hacc[1][2] += g1 * w0.z; hacc[1][3] += g1 * w0.w;
      hacc[1][4] += g1 * w1.x; hacc[1][5] += g1 * w1.y;
      hacc[1][6] += g1 * w1.z; hacc[1][7] += g1 * w1.w;
    }
  }

  // self part: stage x tile into g, then GEMM with w_self
  __syncthreads();
  for (int rr = 0; rr < ROWS / 8; ++rr) {
    int rl = w * (ROWS / 8) + rr;
    int rg = r0 + rl;
    float2 v = make_float2(0.f, 0.f);
    if (rg < N) v = *(const float2*)(x + rg * 128 + lane * 2);
    *(float2*)&g[rl][lane * 2] = v;
  }
  __syncthreads();
  float sacc[2][8];
#pragma unroll
  for (int j = 0; j < 2; ++j)
#pragma unroll
    for (int k = 0; k < 8; ++k) sacc[j][k] = 0.f;
#pragma unroll 4
  for (int i = 0; i < 128; ++i) {
    float g0 = g[ra][i];
    float g1 = g[rb][i];
    float4 w0 = *(const float4*)(wself + i * 128 + ob);
    float4 w1 = *(const float4*)(wself + i * 128 + ob + 4);
    sacc[0][0] += g0 * w0.x; sacc[0][1] += g0 * w0.y;
    sacc[0][2] += g0 * w0.z; sacc[0][3] += g0 * w0.w;
    sacc[0][4] += g0 * w1.x; sacc[0][5] += g0 * w1.y;
    sacc[0][6] += g0 * w1.z; sacc[0][7] += g0 * w1.w;
    sacc[1][0] += g1 * w0.x; sacc[1][1] += g1 * w0.y;
    sacc[1][2] += g1 * w0.z; sacc[1][3] += g1 * w0.w;
    sacc[1][4] += g1 * w1.x; sacc[1][5] += g1 * w1.y;
    sacc[1][6] += g1 * w1.z; sacc[1][7] += g1 * w1.w;
  }

  // LayerNorm per row (reduce across the 16 lanes holding the row)
  float mu[2], rs[2];
#pragma unroll
  for (int j = 0; j < 2; ++j) {
    float a = 0.f, b2 = 0.f;
#pragma unroll
    for (int k = 0; k < 8; ++k) { a += hacc[j][k]; b2 += hacc[j][k] * hacc[j][k]; }
#pragma unroll
    for (int m = 1; m < 16; m <<= 1) {
      a += __shfl_xor(a, m);
      b2 += __shfl_xor(b2, m);
    }
    mu[j] = a * (1.f / 128.f);
    float var = b2 * (1.f / 128.f) - mu[j] * mu[j];
    rs[j] = rsqrtf(fmaxf(var, 0.f) + 1e-5f);
  }

  float4 ga0 = *(const float4*)(gamma + ob);
  float4 ga1 = *(const float4*)(gamma + ob + 4);
  float4 be0 = *(const float4*)(beta + ob);
  float4 be1 = *(const float4*)(beta + ob + 4);
  float4 bi0 = *(const float4*)(bias + ob);
  float4 bi1 = *(const float4*)(bias + ob + 4);
  float gam[8] = {ga0.x, ga0.y, ga0.z, ga0.w, ga1.x, ga1.y, ga1.z, ga1.w};
  float bet[8] = {be0.x, be0.y, be0.z, be0.w, be1.x, be1.y, be1.z, be1.w};
  float bi[8] = {bi0.x, bi0.y, bi0.z, bi0.w, bi1.x, bi1.y, bi1.z, bi1.w};

#pragma unroll
  for (int j = 0; j < 2; ++j) {
    int rg = r0 + ra + j;
    if (rg >= N) continue;
    float o0[8];
#pragma unroll
    for (int k = 0; k < 8; ++k)
      o0[k] = (hacc[j][k] - mu[j]) * rs[j] * gam[k] + bet[k] + bi[k] + sacc[j][k];
    float4* op = (float4*)(out + rg * 128 + ob);
    op[0] = make_float4(o0[0], o0[1], o0[2], o0[3]);
    op[1] = make_float4(o0[4], o0[5], o0[6], o0[7]);
  }
}

extern "C" void kernel_launch(void* const* d_in, const int* in_sizes, int n_in,
                              void* d_out, int out_size, void* d_ws, size_t ws_size,
                              hipStream_t stream) {
  const float* x = (const float*)d_in[0];
  const int* ei = (const int*)d_in[1];
  const int* etype = (const int*)d_in[2];
  const float* ew = (const float*)d_in[3];
  const float* weight = (const float*)d_in[4];
  const float* alpha = (const float*)d_in[5];
  const float* bias = (const float*)d_in[6];
  const float* wself = (const float*)d_in[7];
  const float* gamma = (const float*)d_in[8];
  const float* beta = (const float*)d_in[9];
  float* out = (float*)d_out;

  int N = in_sizes[0] / 128;
  int E = in_sizes[2];
  const int* row = ei;
  const int* col = ei + E;

  float* deg = (float*)d_ws;
  int* cnt = (int*)d_ws + N;
  int* rstart = cnt + N;          // N+1 used, pad to N+4
  int* nxt = rstart + N + 4;
  int* epack = nxt + N;
  float* enw = (float*)(epack + E);
  float* Wc = enw + E;            // NT*128*128 floats, 16B-aligned by construction

  hipMemsetAsync(d_ws, 0, (size_t)2 * N * sizeof(int), stream);
  int eb = (E + 255) / 256;
  k_deg_cnt<<<eb, 256, 0, stream>>>(row, ew, deg, cnt, E);
  k_scan<<<1, 1024, 0, stream>>>(cnt, rstart, nxt, N);
  k_scatter<<<eb, 256, 0, stream>>>(row, col, etype, ew, deg, nxt, epack, enw, E);
  k_wcomb<<<NT * 128, 128, 0, stream>>>(alpha, weight, Wc);
  int mb = (N + ROWS - 1) / ROWS;
  k_main<<<mb, MTHREADS, 0, stream>>>(x, rstart, epack, enw, Wc, wself, gamma, beta,
                                      bias, out, N);
}

// Round 2
// 1562.422 us; speedup vs baseline: 1.0399x; 1.0399x over previous
//
#include <hip/hip_runtime.h>

#define NT 16
#define NB 8
#define ROWS 64
#define MTHREADS 512
#define GPITCH 130

// ---------------- CSR build: (row,type)-keyed ----------------

__global__ void k_count(const int* __restrict__ row, const int* __restrict__ etype,
                        const float* __restrict__ ew, float* __restrict__ deg,
                        int* __restrict__ cnt, int E) {
  int e = blockIdx.x * blockDim.x + threadIdx.x;
  if (e < E) {
    int r = row[e];
    atomicAdd(&deg[r], ew[e]);
    atomicAdd(&cnt[r * NT + etype[e]], 1);
  }
}

__global__ void k_rowtot(const int* __restrict__ cnt, int* __restrict__ rtot, int N) {
  int r = blockIdx.x * blockDim.x + threadIdx.x;
  if (r < N) {
    int s = 0;
#pragma unroll
    for (int t = 0; t < NT; ++t) s += cnt[r * NT + t];
    rtot[r] = s;
  }
}

__global__ __launch_bounds__(1024) void k_scan(const int* __restrict__ v_in,
                                               int* __restrict__ start, int n) {
  __shared__ int wsum[16];
  __shared__ int carry;
  if (threadIdx.x == 0) carry = 0;
  __syncthreads();
  int lane = threadIdx.x & 63;
  int wid = threadIdx.x >> 6;
  for (int base = 0; base < n; base += 1024) {
    int i = base + threadIdx.x;
    int v = (i < n) ? v_in[i] : 0;
    int s = v;
#pragma unroll
    for (int d = 1; d < 64; d <<= 1) {
      int t = __shfl_up(s, d);
      if (lane >= d) s += t;
    }
    if (lane == 63) wsum[wid] = s;
    __syncthreads();
    if (threadIdx.x < 16) {
      int w2 = wsum[threadIdx.x];
#pragma unroll
      for (int d = 1; d < 16; d <<= 1) {
        int t = __shfl_up(w2, d);
        if ((int)threadIdx.x >= d) w2 += t;
      }
      wsum[threadIdx.x] = w2;
    }
    __syncthreads();
    int wofs = (wid > 0) ? wsum[wid - 1] : 0;
    int incl = s + wofs + carry;
    if (i < n) start[i] = incl - v;
    __syncthreads();
    if (threadIdx.x == 1023) carry = incl;
    __syncthreads();
  }
  if (threadIdx.x == 0) start[n] = carry;
}

__global__ void k_rtstart(const int* __restrict__ rstart, const int* __restrict__ cnt,
                          int* __restrict__ rts, int* __restrict__ nxt, int N, int E) {
  int r = blockIdx.x * blockDim.x + threadIdx.x;
  if (r < N) {
    int base = rstart[r];
#pragma unroll
    for (int t = 0; t < NT; ++t) {
      rts[r * NT + t] = base;
      nxt[r * NT + t] = base;
      base += cnt[r * NT + t];
    }
    if (r == N - 1) rts[N * NT] = E;
  }
}

__global__ void k_scatter(const int* __restrict__ row, const int* __restrict__ col,
                          const int* __restrict__ etype, const float* __restrict__ ew,
                          const float* __restrict__ deg, int* __restrict__ nxt,
                          int* __restrict__ ecol, float* __restrict__ enw, int E) {
  int e = blockIdx.x * blockDim.x + threadIdx.x;
  if (e < E) {
    int r = row[e];
    float nw = ew[e] / fmaxf(deg[r], 1e-12f);
    int pos = atomicAdd(&nxt[r * NT + etype[e]], 1);
    ecol[pos] = col[e];
    enw[pos] = nw;
  }
}

// ---------------- basis combine ----------------

__global__ void k_wcomb(const float* __restrict__ alpha, const float* __restrict__ weight,
                        float* __restrict__ Wc) {
  int t = blockIdx.x >> 7;
  int i = blockIdx.x & 127;
  int o = threadIdx.x;
  float s = 0.f;
#pragma unroll
  for (int b = 0; b < NB; ++b)
    s += alpha[t * NB + b] * weight[(b * 128 + i) * 128 + o];
  Wc[(t * 128 + i) * 128 + o] = s;
}

// ---------------- fused aggregate + GEMM + LN + self ----------------

__global__ __launch_bounds__(MTHREADS) void k_main(
    const float* __restrict__ x, const int* __restrict__ rts,
    const int* __restrict__ ecol, const float* __restrict__ enw,
    const float* __restrict__ Wc, const float* __restrict__ wself,
    const float* __restrict__ gamma, const float* __restrict__ beta,
    const float* __restrict__ bias, float* __restrict__ out, int N) {
  __shared__ float g[ROWS][GPITCH];
  int tid = threadIdx.x;
  int lane = tid & 63;
  int w = tid >> 6;  // wave 0..7
  int r0 = blockIdx.x * ROWS;

  int lane16 = tid & 15;
  int rpair = tid >> 4;  // 0..31
  int ob = lane16 * 8;
  int ra = rpair * 2, rb = ra + 1;

  float hacc[2][8];
#pragma unroll
  for (int j = 0; j < 2; ++j)
#pragma unroll
    for (int k = 0; k < 8; ++k) hacc[j][k] = 0.f;

  for (int t = 0; t < NT; ++t) {
    // aggregate per (row,type) sub-segment into registers, one LDS write each
#pragma unroll
    for (int rr = 0; rr < ROWS / 8; ++rr) {
      int rl = w * (ROWS / 8) + rr;
      int rg = r0 + rl;
      float cx = 0.f, cy = 0.f;
      if (rg < N) {
        int sb = rts[rg * NT + t], se = rts[rg * NT + t + 1];
        int e = sb;
        for (; e + 2 <= se; e += 2) {
          int c0 = ecol[e], c1 = ecol[e + 1];
          float w0 = enw[e], w1 = enw[e + 1];
          float2 x0 = *(const float2*)(x + (size_t)c0 * 128 + lane * 2);
          float2 x1 = *(const float2*)(x + (size_t)c1 * 128 + lane * 2);
          cx += w0 * x0.x; cy += w0 * x0.y;
          cx += w1 * x1.x; cy += w1 * x1.y;
        }
        if (e < se) {
          int c0 = ecol[e];
          float w0 = enw[e];
          float2 x0 = *(const float2*)(x + (size_t)c0 * 128 + lane * 2);
          cx += w0 * x0.x; cy += w0 * x0.y;
        }
      }
      g[rl][lane * 2] = cx;
      g[rl][lane * 2 + 1] = cy;
    }
    __syncthreads();
    // GEMM accumulate: hacc += g @ W_t  (2 rows x 8 cols per thread)
    const float* Wt = Wc + t * (128 * 128);
#pragma unroll 4
    for (int i = 0; i < 128; ++i) {
      float g0 = g[ra][i];
      float g1 = g[rb][i];
      float4 w0 = *(const float4*)(Wt + i * 128 + ob);
      float4 w1 = *(const float4*)(Wt + i * 128 + ob + 4);
      hacc[0][0] += g0 * w0.x; hacc[0][1] += g0 * w0.y;
      hacc[0][2] += g0 * w0.z; hacc[0][3] += g0 * w0.w;
      hacc[0][4] += g0 * w1.x; hacc[0][5] += g0 * w1.y;
      hacc[0][6] += g0 * w1.z; hacc[0][7] += g0 * w1.w;
      hacc[1][0] += g1 * w0.x; hacc[1][1] += g1 * w0.y;
      hacc[1][2] += g1 * w0.z; hacc[1][3] += g1 * w0.w;
      hacc[1][4] += g1 * w1.x; hacc[1][5] += g1 * w1.y;
      hacc[1][6] += g1 * w1.z; hacc[1][7] += g1 * w1.w;
    }
    __syncthreads();
  }

  // self part: stage x tile into g, then GEMM with w_self
  for (int rr = 0; rr < ROWS / 8; ++rr) {
    int rl = w * (ROWS / 8) + rr;
    int rg = r0 + rl;
    float2 v = make_float2(0.f, 0.f);
    if (rg < N) v = *(const float2*)(x + (size_t)rg * 128 + lane * 2);
    *(float2*)&g[rl][lane * 2] = v;
  }
  __syncthreads();
  float sacc[2][8];
#pragma unroll
  for (int j = 0; j < 2; ++j)
#pragma unroll
    for (int k = 0; k < 8; ++k) sacc[j][k] = 0.f;
#pragma unroll 4
  for (int i = 0; i < 128; ++i) {
    float g0 = g[ra][i];
    float g1 = g[rb][i];
    float4 w0 = *(const float4*)(wself + i * 128 + ob);
    float4 w1 = *(const float4*)(wself + i * 128 + ob + 4);
    sacc[0][0] += g0 * w0.x; sacc[0][1] += g0 * w0.y;
    sacc[0][2] += g0 * w0.z; sacc[0][3] += g0 * w0.w;
    sacc[0][4] += g0 * w1.x; sacc[0][5] += g0 * w1.y;
    sacc[0][6] += g0 * w1.z; sacc[0][7] += g0 * w1.w;
    sacc[1][0] += g1 * w0.x; sacc[1][1] += g1 * w0.y;
    sacc[1][2] += g1 * w0.z; sacc[1][3] += g1 * w0.w;
    sacc[1][4] += g1 * w1.x; sacc[1][5] += g1 * w1.y;
    sacc[1][6] += g1 * w1.z; sacc[1][7] += g1 * w1.w;
  }

  // LayerNorm per row (reduce across the 16 lanes holding the row)
  float mu[2], rs[2];
#pragma unroll
  for (int j = 0; j < 2; ++j) {
    float a = 0.f, b2 = 0.f;
#pragma unroll
    for (int k = 0; k < 8; ++k) { a += hacc[j][k]; b2 += hacc[j][k] * hacc[j][k]; }
#pragma unroll
    for (int m = 1; m < 16; m <<= 1) {
      a += __shfl_xor(a, m);
      b2 += __shfl_xor(b2, m);
    }
    mu[j] = a * (1.f / 128.f);
    float var = b2 * (1.f / 128.f) - mu[j] * mu[j];
    rs[j] = rsqrtf(fmaxf(var, 0.f) + 1e-5f);
  }

  float4 ga0 = *(const float4*)(gamma + ob);
  float4 ga1 = *(const float4*)(gamma + ob + 4);
  float4 be0 = *(const float4*)(beta + ob);
  float4 be1 = *(const float4*)(beta + ob + 4);
  float4 bi0 = *(const float4*)(bias + ob);
  float4 bi1 = *(const float4*)(bias + ob + 4);
  float gam[8] = {ga0.x, ga0.y, ga0.z, ga0.w, ga1.x, ga1.y, ga1.z, ga1.w};
  float bet[8] = {be0.x, be0.y, be0.z, be0.w, be1.x, be1.y, be1.z, be1.w};
  float bi[8] = {bi0.x, bi0.y, bi0.z, bi0.w, bi1.x, bi1.y, bi1.z, bi1.w};

#pragma unroll
  for (int j = 0; j < 2; ++j) {
    int rg = r0 + ra + j;
    if (rg >= N) continue;
    float o0[8];
#pragma unroll
    for (int k = 0; k < 8; ++k)
      o0[k] = (hacc[j][k] - mu[j]) * rs[j] * gam[k] + bet[k] + bi[k] + sacc[j][k];
    float4* op = (float4*)(out + (size_t)rg * 128 + ob);
    op[0] = make_float4(o0[0], o0[1], o0[2], o0[3]);
    op[1] = make_float4(o0[4], o0[5], o0[6], o0[7]);
  }
}

extern "C" void kernel_launch(void* const* d_in, const int* in_sizes, int n_in,
                              void* d_out, int out_size, void* d_ws, size_t ws_size,
                              hipStream_t stream) {
  const float* x = (const float*)d_in[0];
  const int* ei = (const int*)d_in[1];
  const int* etype = (const int*)d_in[2];
  const float* ew = (const float*)d_in[3];
  const float* weight = (const float*)d_in[4];
  const float* alpha = (const float*)d_in[5];
  const float* bias = (const float*)d_in[6];
  const float* wself = (const float*)d_in[7];
  const float* gamma = (const float*)d_in[8];
  const float* beta = (const float*)d_in[9];
  float* out = (float*)d_out;

  int N = in_sizes[0] / 128;
  int E = in_sizes[2];
  const int* row = ei;
  const int* col = ei + E;

  // ws layout (4B units)
  float* deg = (float*)d_ws;               // N
  int* cnt = (int*)d_ws + N;               // N*NT
  int* rtot = cnt + (size_t)N * NT;        // N
  int* rstart = rtot + N;                  // N+1 (+pad)
  int* rts = rstart + N + 4;               // N*NT+1 (+pad)
  int* nxt = rts + (size_t)N * NT + 4;     // N*NT
  int* ecol = nxt + (size_t)N * NT;        // E
  float* enw = (float*)(ecol + E);         // E
  float* Wc = enw + E;                     // NT*128*128

  hipMemsetAsync(d_ws, 0, (size_t)(N + (size_t)N * NT) * sizeof(int), stream);
  int eb = (E + 255) / 256;
  int nb = (N + 255) / 256;
  k_count<<<eb, 256, 0, stream>>>(row, etype, ew, deg, cnt, E);
  k_rowtot<<<nb, 256, 0, stream>>>(cnt, rtot, N);
  k_scan<<<1, 1024, 0, stream>>>(rtot, rstart, N);
  k_rtstart<<<nb, 256, 0, stream>>>(rstart, cnt, rts, nxt, N, E);
  k_scatter<<<eb, 256, 0, stream>>>(row, col, etype, ew, deg, nxt, ecol, enw, E);
  k_wcomb<<<NT * 128, 128, 0, stream>>>(alpha, weight, Wc);
  int mb = (N + ROWS - 1) / ROWS;
  k_main<<<mb, MTHREADS, 0, stream>>>(x, rts, ecol, enw, Wc, wself, gamma, beta,
                                      bias, out, N);
}

// Round 3
// 595.975 us; speedup vs baseline: 2.7262x; 2.6216x over previous
//
#include <hip/hip_runtime.h>

#define NT 16
#define NB 8

typedef __attribute__((ext_vector_type(8))) short short8;
typedef __attribute__((ext_vector_type(4))) float f32x4;

__device__ __forceinline__ unsigned short f2bf(float f) {
  unsigned int u = __float_as_uint(f);
  u += 0x7FFFu + ((u >> 16) & 1u);
  return (unsigned short)(u >> 16);
}
__device__ __forceinline__ unsigned int packbf2(float a, float b) {
  return (unsigned int)f2bf(a) | ((unsigned int)f2bf(b) << 16);
}

// ---------------- CSR build: (row,type)-keyed ----------------

__global__ void k_count(const int* __restrict__ row, const int* __restrict__ etype,
                        const float* __restrict__ ew, float* __restrict__ deg,
                        int* __restrict__ cnt, int E) {
  int e = blockIdx.x * blockDim.x + threadIdx.x;
  if (e < E) {
    int r = row[e];
    atomicAdd(&deg[r], ew[e]);
    atomicAdd(&cnt[r * NT + etype[e]], 1);
  }
}

__global__ void k_rowtot(const int* __restrict__ cnt, int* __restrict__ rtot, int N) {
  int r = blockIdx.x * blockDim.x + threadIdx.x;
  if (r < N) {
    int s = 0;
#pragma unroll
    for (int t = 0; t < NT; ++t) s += cnt[r * NT + t];
    rtot[r] = s;
  }
}

__global__ __launch_bounds__(256) void k_scan_local(const int* __restrict__ rtot,
                                                    int* __restrict__ rstart,
                                                    int* __restrict__ bsum, int n) {
  __shared__ int ws[4];
  int tid = threadIdx.x;
  int i = blockIdx.x * 256 + tid;
  int lane = tid & 63, w = tid >> 6;
  int v = (i < n) ? rtot[i] : 0;
  int s = v;
#pragma unroll
  for (int d = 1; d < 64; d <<= 1) {
    int t = __shfl_up(s, d);
    if (lane >= d) s += t;
  }
  if (lane == 63) ws[w] = s;
  __syncthreads();
  int add = 0;
  for (int j = 0; j < w; ++j) add += ws[j];
  if (i < n) rstart[i] = s + add - v;
  if (tid == 255) bsum[blockIdx.x] = s + add;
}

__global__ __launch_bounds__(256) void k_scan_small(const int* __restrict__ bsum,
                                                    int* __restrict__ bsumx, int nb) {
  __shared__ int ws[4];
  int tid = threadIdx.x;
  int lane = tid & 63, w = tid >> 6;
  int v = (tid < nb) ? bsum[tid] : 0;
  int s = v;
#pragma unroll
  for (int d = 1; d < 64; d <<= 1) {
    int t = __shfl_up(s, d);
    if (lane >= d) s += t;
  }
  if (lane == 63) ws[w] = s;
  __syncthreads();
  int add = 0;
  for (int j = 0; j < w; ++j) add += ws[j];
  if (tid < nb) bsumx[tid] = s + add - v;
}

__global__ void k_scan_add(int* __restrict__ rstart, const int* __restrict__ bsumx, int n) {
  int i = blockIdx.x * 256 + threadIdx.x;
  if (i < n) rstart[i] += bsumx[blockIdx.x];
}

__global__ void k_rtstart(const int* __restrict__ rstart, const int* __restrict__ cnt,
                          int* __restrict__ rts, int* __restrict__ nxt, int N, int E) {
  int r = blockIdx.x * blockDim.x + threadIdx.x;
  if (r < N) {
    int base = rstart[r];
#pragma unroll
    for (int t = 0; t < NT; ++t) {
      rts[r * NT + t] = base;
      nxt[r * NT + t] = base;
      base += cnt[r * NT + t];
    }
    if (r == N - 1) rts[N * NT] = E;
  }
}

__global__ void k_scatter(const int* __restrict__ row, const int* __restrict__ col,
                          const int* __restrict__ etype, const float* __restrict__ ew,
                          const float* __restrict__ deg, int* __restrict__ nxt,
                          int2* __restrict__ epk, int E) {
  int e = blockIdx.x * blockDim.x + threadIdx.x;
  if (e < E) {
    int r = row[e];
    float nw = ew[e] / fmaxf(deg[r], 1e-12f);
    int pos = atomicAdd(&nxt[r * NT + etype[e]], 1);
    epk[pos] = make_int2(col[e], __float_as_int(nw));
  }
}

// ---------------- weight prep: bf16, B-fragment layout ----------------
// WcB index: ((((t*8+ct)*4+ks)*4+lq)*16+n15)*8+j  <-  Wc[t][k][n],
//   k = ks*32 + lq*8 + j, n = ct*16 + n15

__global__ void k_wprep(const float* __restrict__ alpha, const float* __restrict__ weight,
                        const float* __restrict__ wself, unsigned short* __restrict__ WcB,
                        unsigned short* __restrict__ wselfB) {
  int idx = blockIdx.x * 256 + threadIdx.x;
  const int TOT = NT * 128 * 128;
  if (idx < TOT) {
    int t = idx >> 14, k = (idx >> 7) & 127, n = idx & 127;
    float s = 0.f;
#pragma unroll
    for (int b = 0; b < NB; ++b) s += alpha[t * NB + b] * weight[(b * 128 + k) * 128 + n];
    int ct = n >> 4, n15 = n & 15, ks = k >> 5, lq = (k >> 3) & 3, j = k & 7;
    WcB[(size_t)((((t * 8 + ct) * 4 + ks) * 4 + lq) * 16 + n15) * 8 + j] = f2bf(s);
  } else if (idx < TOT + 128 * 128) {
    int i2 = idx - TOT;
    int k = i2 >> 7, n = i2 & 127;
    float s = wself[k * 128 + n];
    int ct = n >> 4, n15 = n & 15, ks = k >> 5, lq = (k >> 3) & 3, j = k & 7;
    wselfB[((((ct * 4 + ks) * 4 + lq) * 16 + n15) * 8 + j)] = f2bf(s);
  }
}

// ---------------- fused aggregate + MFMA + LN + self, wave-independent -------

__global__ __launch_bounds__(256, 4) void k_main(
    const float* __restrict__ x, const int* __restrict__ rts,
    const int2* __restrict__ epk, const unsigned short* __restrict__ WcB,
    const unsigned short* __restrict__ wselfB, const float* __restrict__ gamma,
    const float* __restrict__ beta, const float* __restrict__ bias,
    float* __restrict__ out, int N) {
  __shared__ unsigned int gts[4][16][68];  // per-wave 16 rows x 136 bf16 (272B pitch)
  int tid = threadIdx.x;
  int lane = tid & 63;
  int wid = tid >> 6;
  int l15 = lane & 15, lq = lane >> 4;
  int rbase = blockIdx.x * 64 + wid * 16;

  unsigned int* gw = &gts[wid][0][0];

  f32x4 acc[8];
#pragma unroll
  for (int ct = 0; ct < 8; ++ct) acc[ct] = (f32x4)0.f;

  for (int t = 0; t < NT; ++t) {
    // preload all 16 row bounds for this type with one wave-wide load
    int bval = 0;
    if (lane < 32) {
      int rr = rbase + l15;
      if (rr < N) bval = rts[rr * NT + t + lq];  // lanes 0-15: start, 16-31: end
    }
    // aggregate each row's (row,type) segment into registers, one LDS write per row
#pragma unroll 1
    for (int i = 0; i < 16; ++i) {
      int sb = __shfl(bval, i);
      int se = __shfl(bval, 16 + i);
      float cx = 0.f, cy = 0.f;
      int e = sb;
      for (; e + 2 <= se; e += 2) {
        int2 p0 = epk[e], p1 = epk[e + 1];
        float2 x0 = *(const float2*)(x + (size_t)p0.x * 128 + 2 * lane);
        float2 x1 = *(const float2*)(x + (size_t)p1.x * 128 + 2 * lane);
        float w0 = __int_as_float(p0.y), w1 = __int_as_float(p1.y);
        cx += w0 * x0.x; cy += w0 * x0.y;
        cx += w1 * x1.x; cy += w1 * x1.y;
      }
      if (e < se) {
        int2 p0 = epk[e];
        float2 x0 = *(const float2*)(x + (size_t)p0.x * 128 + 2 * lane);
        float w0 = __int_as_float(p0.y);
        cx += w0 * x0.x; cy += w0 * x0.y;
      }
      gw[i * 68 + lane] = packbf2(cx, cy);
    }
    // MFMA: acc += g16 @ W_t   (A from LDS, B from global bf16, both frag-order)
    const unsigned short* Wt = WcB + (size_t)t * (8 * 4 * 4 * 16 * 8);
#pragma unroll
    for (int ks = 0; ks < 4; ++ks) {
      short8 a = *(const short8*)((const char*)gw + l15 * 272 + ks * 64 + lq * 16);
#pragma unroll
      for (int ct = 0; ct < 8; ++ct) {
        short8 b = *(const short8*)(Wt + (((ct * 4 + ks) * 4 + lq) * 16 + l15) * 8);
        acc[ct] = __builtin_amdgcn_mfma_f32_16x16x32_bf16(a, b, acc[ct], 0, 0, 0);
      }
    }
  }

  // LayerNorm: D layout col = l15 + 16*ct, row = lq*4 + reg
  float mu[4], rs[4];
#pragma unroll
  for (int reg = 0; reg < 4; ++reg) {
    float s1 = 0.f, s2 = 0.f;
#pragma unroll
    for (int ct = 0; ct < 8; ++ct) { float v = acc[ct][reg]; s1 += v; s2 += v * v; }
#pragma unroll
    for (int m = 1; m < 16; m <<= 1) { s1 += __shfl_xor(s1, m); s2 += __shfl_xor(s2, m); }
    float mmu = s1 * (1.f / 128.f);
    float var = s2 * (1.f / 128.f) - mmu * mmu;
    mu[reg] = mmu;
    rs[reg] = rsqrtf(fmaxf(var, 0.f) + 1e-5f);
  }
  float gam[8], bet[8], bi[8];
#pragma unroll
  for (int ct = 0; ct < 8; ++ct) {
    int cc = ct * 16 + l15;
    gam[ct] = gamma[cc]; bet[ct] = beta[cc]; bi[ct] = bias[cc];
  }
#pragma unroll
  for (int ct = 0; ct < 8; ++ct)
#pragma unroll
    for (int reg = 0; reg < 4; ++reg)
      acc[ct][reg] = (acc[ct][reg] - mu[reg]) * rs[reg] * gam[ct] + bet[ct] + bi[ct];

  // self term: acc += x16 @ w_self (MFMA accumulates into post-LN values)
#pragma unroll 1
  for (int i = 0; i < 16; ++i) {
    int rg = rbase + i;
    float2 v = make_float2(0.f, 0.f);
    if (rg < N) v = *(const float2*)(x + (size_t)rg * 128 + 2 * lane);
    gw[i * 68 + lane] = packbf2(v.x, v.y);
  }
#pragma unroll
  for (int ks = 0; ks < 4; ++ks) {
    short8 a = *(const short8*)((const char*)gw + l15 * 272 + ks * 64 + lq * 16);
#pragma unroll
    for (int ct = 0; ct < 8; ++ct) {
      short8 b = *(const short8*)(wselfB + (((ct * 4 + ks) * 4 + lq) * 16 + l15) * 8);
      acc[ct] = __builtin_amdgcn_mfma_f32_16x16x32_bf16(a, b, acc[ct], 0, 0, 0);
    }
  }

  // store
#pragma unroll
  for (int reg = 0; reg < 4; ++reg) {
    int rg = rbase + lq * 4 + reg;
    if (rg < N) {
#pragma unroll
      for (int ct = 0; ct < 8; ++ct)
        out[(size_t)rg * 128 + ct * 16 + l15] = acc[ct][reg];
    }
  }
}

extern "C" void kernel_launch(void* const* d_in, const int* in_sizes, int n_in,
                              void* d_out, int out_size, void* d_ws, size_t ws_size,
                              hipStream_t stream) {
  const float* x = (const float*)d_in[0];
  const int* ei = (const int*)d_in[1];
  const int* etype = (const int*)d_in[2];
  const float* ew = (const float*)d_in[3];
  const float* weight = (const float*)d_in[4];
  const float* alpha = (const float*)d_in[5];
  const float* bias = (const float*)d_in[6];
  const float* wself = (const float*)d_in[7];
  const float* gamma = (const float*)d_in[8];
  const float* beta = (const float*)d_in[9];
  float* out = (float*)d_out;

  int N = in_sizes[0] / 128;
  int E = in_sizes[2];
  const int* row = ei;
  const int* col = ei + E;

  // ws layout (4-byte units, 16B-aligned chunks)
  int* base = (int*)d_ws;
  size_t o = 0;
  auto N4 = [](size_t v) { return (v + 3) & ~(size_t)3; };
  float* deg = (float*)(base + o); o += N4(N);
  int* cnt = base + o; o += N4((size_t)N * NT);
  int* rtot = base + o; o += N4(N);
  int* rstart = base + o; o += N4(N);
  int* rts = base + o; o += N4((size_t)N * NT + 1);
  int* nxt = base + o; o += N4((size_t)N * NT);
  int* bsum = base + o; o += 256;
  int* bsumx = base + o; o += 256;
  int2* epk = (int2*)(base + o); o += (size_t)2 * E;
  unsigned short* WcB = (unsigned short*)(base + o); o += (size_t)NT * 128 * 128 / 2;
  unsigned short* wselfB = (unsigned short*)(base + o); o += 128 * 128 / 2;

  hipMemsetAsync(d_ws, 0, (N4(N) + N4((size_t)N * NT)) * sizeof(int), stream);
  int eb = (E + 255) / 256;
  int nb = (N + 255) / 256;
  k_count<<<eb, 256, 0, stream>>>(row, etype, ew, deg, cnt, E);
  k_rowtot<<<nb, 256, 0, stream>>>(cnt, rtot, N);
  k_scan_local<<<nb, 256, 0, stream>>>(rtot, rstart, bsum, N);
  k_scan_small<<<1, 256, 0, stream>>>(bsum, bsumx, nb);
  k_scan_add<<<nb, 256, 0, stream>>>(rstart, bsumx, N);
  k_rtstart<<<nb, 256, 0, stream>>>(rstart, cnt, rts, nxt, N, E);
  k_scatter<<<eb, 256, 0, stream>>>(row, col, etype, ew, deg, nxt, epk, E);
  k_wprep<<<(NT * 128 * 128 + 128 * 128 + 255) / 256, 256, 0, stream>>>(
      alpha, weight, wself, WcB, wselfB);
  k_main<<<(N + 63) / 64, 256, 0, stream>>>(x, rts, epk, WcB, wselfB, gamma, beta,
                                            bias, out, N);
}

// Round 4
// 446.467 us; speedup vs baseline: 3.6391x; 1.3349x over previous
//
#include <hip/hip_runtime.h>

#define NT 16
#define NB 8

typedef __attribute__((ext_vector_type(8))) short short8;
typedef __attribute__((ext_vector_type(4))) float f32x4;

__device__ __forceinline__ unsigned short f2bf(float f) {
  unsigned int u = __float_as_uint(f);
  u += 0x7FFFu + ((u >> 16) & 1u);
  return (unsigned short)(u >> 16);
}
__device__ __forceinline__ unsigned int packbf2(float a, float b) {
  return (unsigned int)f2bf(a) | ((unsigned int)f2bf(b) << 16);
}

// ---------------- row-CSR build ----------------

__global__ void k_count(const int* __restrict__ row, const float* __restrict__ ew,
                        float* __restrict__ deg, int* __restrict__ cnt, int E) {
  int e = blockIdx.x * blockDim.x + threadIdx.x;
  if (e < E) {
    int r = row[e];
    atomicAdd(&deg[r], ew[e]);
    atomicAdd(&cnt[r], 1);
  }
}

__global__ __launch_bounds__(256) void k_scan_local(const int* __restrict__ cnt,
                                                    int* __restrict__ rstart,
                                                    int* __restrict__ bsum, int n) {
  __shared__ int ws[4];
  int tid = threadIdx.x;
  int i = blockIdx.x * 256 + tid;
  int lane = tid & 63, w = tid >> 6;
  int v = (i < n) ? cnt[i] : 0;
  int s = v;
#pragma unroll
  for (int d = 1; d < 64; d <<= 1) {
    int t = __shfl_up(s, d);
    if (lane >= d) s += t;
  }
  if (lane == 63) ws[w] = s;
  __syncthreads();
  int add = 0;
  for (int j = 0; j < w; ++j) add += ws[j];
  if (i < n) rstart[i] = s + add - v;
  if (tid == 255) bsum[blockIdx.x] = s + add;
}

__global__ __launch_bounds__(256) void k_scan_small(const int* __restrict__ bsum,
                                                    int* __restrict__ bsumx, int nb) {
  __shared__ int ws[4];
  int tid = threadIdx.x;
  int lane = tid & 63, w = tid >> 6;
  int v = (tid < nb) ? bsum[tid] : 0;
  int s = v;
#pragma unroll
  for (int d = 1; d < 64; d <<= 1) {
    int t = __shfl_up(s, d);
    if (lane >= d) s += t;
  }
  if (lane == 63) ws[w] = s;
  __syncthreads();
  int add = 0;
  for (int j = 0; j < w; ++j) add += ws[j];
  if (tid < nb) bsumx[tid] = s + add - v;
}

__global__ void k_scan_add(int* __restrict__ rstart, int* __restrict__ nxt,
                           const int* __restrict__ bsumx, int n) {
  int i = blockIdx.x * 256 + threadIdx.x;
  if (i < n) {
    int v = rstart[i] + bsumx[blockIdx.x];
    rstart[i] = v;
    nxt[i] = v;
  }
}

__global__ void k_scatter(const int* __restrict__ row, const int* __restrict__ col,
                          const int* __restrict__ etype, const float* __restrict__ ew,
                          int* __restrict__ nxt, int2* __restrict__ epk, int E) {
  int e = blockIdx.x * blockDim.x + threadIdx.x;
  if (e < E) {
    int r = row[e];
    int pos = atomicAdd(&nxt[r], 1);
    epk[pos] = make_int2(col[e] | (etype[e] << 16), __float_as_int(ew[e]));
  }
}

// ---------------- weight prep: bf16 B-fragment layouts (R3-verified) ----------
// WbB index: ((((b*8+ct)*4+ks)*4+lq)*16+n15)*8+j  <-  weight[b][k][n],
//   k = ks*32 + lq*8 + j, n = ct*16 + n15

__global__ void k_wprep(const float* __restrict__ weight, const float* __restrict__ wself,
                        unsigned short* __restrict__ WbB,
                        unsigned short* __restrict__ wselfB) {
  int idx = blockIdx.x * 256 + threadIdx.x;
  const int TOT = NB * 128 * 128;
  if (idx < TOT) {
    int b = idx >> 14, k = (idx >> 7) & 127, n = idx & 127;
    float s = weight[(size_t)(b * 128 + k) * 128 + n];
    int ct = n >> 4, n15 = n & 15, ks = k >> 5, lq = (k >> 3) & 3, j = k & 7;
    WbB[(size_t)((((b * 8 + ct) * 4 + ks) * 4 + lq) * 16 + n15) * 8 + j] = f2bf(s);
  } else if (idx < TOT + 128 * 128) {
    int i2 = idx - TOT;
    int k = i2 >> 7, n = i2 & 127;
    float s = wself[k * 128 + n];
    int ct = n >> 4, n15 = n & 15, ks = k >> 5, lq = (k >> 3) & 3, j = k & 7;
    wselfB[((((ct * 4 + ks) * 4 + lq) * 16 + n15) * 8 + j)] = f2bf(s);
  }
}

// ---------------- fused: basis aggregate + MFMA + LN + self ----------------
// block = 256 threads = 16 groups of 16 lanes; block owns 16 rows.

__global__ __launch_bounds__(256, 4) void k_main(
    const float* __restrict__ x, const int* __restrict__ rstart,
    const int2* __restrict__ epk, const float* __restrict__ alpha,
    const float* __restrict__ deg, const unsigned short* __restrict__ WbB,
    const unsigned short* __restrict__ wselfB, const float* __restrict__ gamma,
    const float* __restrict__ beta, const float* __restrict__ bias,
    float* __restrict__ out, int N, int E) {
  __shared__ unsigned short g[NB][2048];   // [b][16 rows x 128 feats] bf16, XOR-swizzled
  __shared__ unsigned short xs[2048];      // self x-tile, same swizzle
  __shared__ float alds[NT * NB];
  __shared__ float2 stats[16][4];

  int tid = threadIdx.x;
  int lane = tid & 63;
  int wid = tid >> 6;
  int gi = tid >> 4;       // group 0..15 = local row
  int l = tid & 15;        // lane in group
  int l15 = lane & 15, lq = lane >> 4;
  int rbase = blockIdx.x * 16;

  if (tid < NT * NB) alds[tid] = alpha[tid];
  __syncthreads();

  // ---- phase 1: per-row basis aggregation (group gi owns row rbase+gi) ----
  int r = rbase + gi;
  float acc[8][8];
#pragma unroll
  for (int b = 0; b < 8; ++b)
#pragma unroll
    for (int j = 0; j < 8; ++j) acc[b][j] = 0.f;

  // self x-tile staging (independent of edge walk)
  {
    float4 x0 = make_float4(0.f, 0.f, 0.f, 0.f), x1 = x0;
    if (r < N) {
      const float4* xp = (const float4*)(x + (size_t)r * 128 + l * 8);
      x0 = xp[0];
      x1 = xp[1];
    }
    unsigned int p0 = packbf2(x0.x, x0.y), p1 = packbf2(x0.z, x0.w);
    unsigned int p2 = packbf2(x1.x, x1.y), p3 = packbf2(x1.z, x1.w);
    int off = gi * 256 + ((l * 16) ^ ((gi & 7) << 4));
    *(uint4*)((char*)xs + off) = make_uint4(p0, p1, p2, p3);
  }

  int sb = 0, se = 0;
  if (r < N) {
    sb = rstart[r];
    se = (r == N - 1) ? E : rstart[r + 1];
  }
  for (int e = sb; e < se; ++e) {
    int2 p = epk[e];
    int c = p.x & 0xFFFF;
    int t = (p.x >> 16) & 15;
    float w_ = __int_as_float(p.y);
    const float4* xp = (const float4*)(x + (size_t)c * 128 + l * 8);
    float4 x0 = xp[0], x1 = xp[1];
    float4 a0 = *(const float4*)&alds[t * 8];
    float4 a1 = *(const float4*)&alds[t * 8 + 4];
    float cf[8] = {w_ * a0.x, w_ * a0.y, w_ * a0.z, w_ * a0.w,
                   w_ * a1.x, w_ * a1.y, w_ * a1.z, w_ * a1.w};
    float xv[8] = {x0.x, x0.y, x0.z, x0.w, x1.x, x1.y, x1.z, x1.w};
#pragma unroll
    for (int b = 0; b < 8; ++b) {
      float cb = cf[b];
#pragma unroll
      for (int j = 0; j < 8; ++j) acc[b][j] += cb * xv[j];
    }
  }

  // scale by 1/deg (linear, exact same values as per-edge normalization)
  float rdeg = 1.f / fmaxf((r < N) ? deg[r] : 1.f, 1e-12f);
#pragma unroll
  for (int b = 0; b < 8; ++b) {
#pragma unroll
    for (int j = 0; j < 8; ++j) acc[b][j] *= rdeg;
    unsigned int p0 = packbf2(acc[b][0], acc[b][1]);
    unsigned int p1 = packbf2(acc[b][2], acc[b][3]);
    unsigned int p2 = packbf2(acc[b][4], acc[b][5]);
    unsigned int p3 = packbf2(acc[b][6], acc[b][7]);
    int off = gi * 256 + ((l * 16) ^ ((gi & 7) << 4));
    *(uint4*)((char*)&g[b][0] + off) = make_uint4(p0, p1, p2, p3);
  }
  __syncthreads();

  // ---- phase 2: MFMA. wave wid owns ct = {2*wid, 2*wid+1} ----
  f32x4 accA[2], accS[2];
  accA[0] = (f32x4)0.f; accA[1] = (f32x4)0.f;
  accS[0] = (f32x4)0.f; accS[1] = (f32x4)0.f;
  int ct0 = wid * 2;

#pragma unroll
  for (int b = 0; b < 8; ++b) {
#pragma unroll
    for (int ks = 0; ks < 4; ++ks) {
      short8 a = *(const short8*)((const char*)&g[b][0] + l15 * 256 +
                                  ((ks * 64 + lq * 16) ^ ((l15 & 7) << 4)));
#pragma unroll
      for (int ci = 0; ci < 2; ++ci) {
        int ct = ct0 + ci;
        short8 bf = *(const short8*)(WbB +
            (size_t)((((b * 8 + ct) * 4 + ks) * 4 + lq) * 16 + l15) * 8);
        accA[ci] = __builtin_amdgcn_mfma_f32_16x16x32_bf16(a, bf, accA[ci], 0, 0, 0);
      }
    }
  }
#pragma unroll
  for (int ks = 0; ks < 4; ++ks) {
    short8 a = *(const short8*)((const char*)xs + l15 * 256 +
                                ((ks * 64 + lq * 16) ^ ((l15 & 7) << 4)));
#pragma unroll
    for (int ci = 0; ci < 2; ++ci) {
      int ct = ct0 + ci;
      short8 bf = *(const short8*)(wselfB +
          (size_t)(((ct * 4 + ks) * 4 + lq) * 16 + l15) * 8);
      accS[ci] = __builtin_amdgcn_mfma_f32_16x16x32_bf16(a, bf, accS[ci], 0, 0, 0);
    }
  }

  // ---- phase 3: LN stats (cross-wave via LDS) + epilogue ----
#pragma unroll
  for (int reg = 0; reg < 4; ++reg) {
    float v0 = accA[0][reg], v1 = accA[1][reg];
    float s1 = v0 + v1;
    float s2 = v0 * v0 + v1 * v1;
#pragma unroll
    for (int m = 1; m < 16; m <<= 1) {
      s1 += __shfl_xor(s1, m);
      s2 += __shfl_xor(s2, m);
    }
    if (l15 == 0) stats[lq * 4 + reg][wid] = make_float2(s1, s2);
  }
  __syncthreads();

  int c0 = ct0 * 16 + l15, c1 = c0 + 16;
  float g0 = gamma[c0], g1 = gamma[c1];
  float be0 = beta[c0], be1 = beta[c1];
  float bb0 = bias[c0], bb1 = bias[c1];
#pragma unroll
  for (int reg = 0; reg < 4; ++reg) {
    int rowl = lq * 4 + reg;
    float2 p0 = stats[rowl][0], p1 = stats[rowl][1];
    float2 p2 = stats[rowl][2], p3 = stats[rowl][3];
    float S1 = p0.x + p1.x + p2.x + p3.x;
    float S2 = p0.y + p1.y + p2.y + p3.y;
    float mu = S1 * (1.f / 128.f);
    float var = S2 * (1.f / 128.f) - mu * mu;
    float rs = rsqrtf(fmaxf(var, 0.f) + 1e-5f);
    int rg = rbase + rowl;
    if (rg < N) {
      out[(size_t)rg * 128 + c0] =
          (accA[0][reg] - mu) * rs * g0 + be0 + bb0 + accS[0][reg];
      out[(size_t)rg * 128 + c1] =
          (accA[1][reg] - mu) * rs * g1 + be1 + bb1 + accS[1][reg];
    }
  }
}

extern "C" void kernel_launch(void* const* d_in, const int* in_sizes, int n_in,
                              void* d_out, int out_size, void* d_ws, size_t ws_size,
                              hipStream_t stream) {
  const float* x = (const float*)d_in[0];
  const int* ei = (const int*)d_in[1];
  const int* etype = (const int*)d_in[2];
  const float* ew = (const float*)d_in[3];
  const float* weight = (const float*)d_in[4];
  const float* alpha = (const float*)d_in[5];
  const float* bias = (const float*)d_in[6];
  const float* wself = (const float*)d_in[7];
  const float* gamma = (const float*)d_in[8];
  const float* beta = (const float*)d_in[9];
  float* out = (float*)d_out;

  int N = in_sizes[0] / 128;
  int E = in_sizes[2];
  const int* row = ei;
  const int* col = ei + E;

  int* base = (int*)d_ws;
  size_t o = 0;
  auto N4 = [](size_t v) { return (v + 3) & ~(size_t)3; };
  float* deg = (float*)(base + o); o += N4(N);
  int* cnt = base + o; o += N4(N);
  int* rstart = base + o; o += N4(N);
  int* nxt = base + o; o += N4(N);
  int* bsum = base + o; o += 256;
  int* bsumx = base + o; o += 256;
  int2* epk = (int2*)(base + o); o += (size_t)2 * E;
  unsigned short* WbB = (unsigned short*)(base + o); o += (size_t)NB * 128 * 128 / 2;
  unsigned short* wselfB = (unsigned short*)(base + o); o += 128 * 128 / 2;

  hipMemsetAsync(d_ws, 0, 2 * N4(N) * sizeof(int), stream);
  int eb = (E + 255) / 256;
  int nb = (N + 255) / 256;
  k_count<<<eb, 256, 0, stream>>>(row, ew, deg, cnt, E);
  k_scan_local<<<nb, 256, 0, stream>>>(cnt, rstart, bsum, N);
  k_scan_small<<<1, 256, 0, stream>>>(bsum, bsumx, nb);
  k_scan_add<<<nb, 256, 0, stream>>>(rstart, nxt, bsumx, N);
  k_scatter<<<eb, 256, 0, stream>>>(row, col, etype, ew, nxt, epk, E);
  k_wprep<<<(NB * 128 * 128 + 128 * 128 + 255) / 256, 256, 0, stream>>>(
      weight, wself, WbB, wselfB);
  k_main<<<(N + 15) / 16, 256, 0, stream>>>(x, rstart, epk, alpha, deg, WbB, wselfB,
                                            gamma, beta, bias, out, N, E);
}

// Round 5
// 297.531 us; speedup vs baseline: 5.4608x; 1.5006x over previous
//
#include <hip/hip_runtime.h>

#define NT 16
#define NB 8
#define CAP 72

typedef __attribute__((ext_vector_type(8))) short short8;
typedef __attribute__((ext_vector_type(4))) float f32x4;

__device__ __forceinline__ unsigned short f2bf(float f) {
  unsigned int u = __float_as_uint(f);
  u += 0x7FFFu + ((u >> 16) & 1u);
  return (unsigned short)(u >> 16);
}
__device__ __forceinline__ unsigned int packbf2(float a, float b) {
  return (unsigned int)f2bf(a) | ((unsigned int)f2bf(b) << 16);
}

// ---------------- x -> bf16 ----------------

__global__ void k_xprep(const float* __restrict__ x, unsigned short* __restrict__ xb,
                        int total8) {
  int i = blockIdx.x * 256 + threadIdx.x;
  if (i < total8) {
    const float4* p = (const float4*)(x + (size_t)i * 8);
    float4 v0 = p[0], v1 = p[1];
    uint4 q = make_uint4(packbf2(v0.x, v0.y), packbf2(v0.z, v0.w),
                         packbf2(v1.x, v1.y), packbf2(v1.z, v1.w));
    *(uint4*)(xb + (size_t)i * 8) = q;
  }
}

// ---------------- weight prep: bf16 B-fragment layouts (R3/R4-verified) -------

__global__ void k_wprep(const float* __restrict__ weight, const float* __restrict__ wself,
                        unsigned short* __restrict__ WbB,
                        unsigned short* __restrict__ wselfB) {
  int idx = blockIdx.x * 256 + threadIdx.x;
  const int TOT = NB * 128 * 128;
  if (idx < TOT) {
    int b = idx >> 14, k = (idx >> 7) & 127, n = idx & 127;
    float s = weight[(size_t)(b * 128 + k) * 128 + n];
    int ct = n >> 4, n15 = n & 15, ks = k >> 5, lq = (k >> 3) & 3, j = k & 7;
    WbB[(size_t)((((b * 8 + ct) * 4 + ks) * 4 + lq) * 16 + n15) * 8 + j] = f2bf(s);
  } else if (idx < TOT + 128 * 128) {
    int i2 = idx - TOT;
    int k = i2 >> 7, n = i2 & 127;
    float s = wself[k * 128 + n];
    int ct = n >> 4, n15 = n & 15, ks = k >> 5, lq = (k >> 3) & 3, j = k & 7;
    wselfB[((((ct * 4 + ks) * 4 + lq) * 16 + n15) * 8 + j)] = f2bf(s);
  }
}

// ---------------- binned single-pass scatter ----------------

__global__ void k_scatter_bin(const int* __restrict__ row, const int* __restrict__ col,
                              const int* __restrict__ etype, const float* __restrict__ ew,
                              int* __restrict__ rcnt, int2* __restrict__ epk, int E) {
  int e = blockIdx.x * blockDim.x + threadIdx.x;
  if (e < E) {
    int r = row[e];
    int pos = atomicAdd(&rcnt[r], 1);
    if (pos < CAP)
      epk[(size_t)r * CAP + pos] = make_int2(col[e] | (etype[e] << 16),
                                             __float_as_int(ew[e]));
  }
}

// ---------------- CSR fallback path ----------------

__global__ void k_count(const int* __restrict__ row, int* __restrict__ cnt, int E) {
  int e = blockIdx.x * blockDim.x + threadIdx.x;
  if (e < E) atomicAdd(&cnt[row[e]], 1);
}

__global__ __launch_bounds__(256) void k_scan_local(const int* __restrict__ cnt,
                                                    int* __restrict__ rstart,
                                                    int* __restrict__ bsum, int n) {
  __shared__ int ws[4];
  int tid = threadIdx.x;
  int i = blockIdx.x * 256 + tid;
  int lane = tid & 63, w = tid >> 6;
  int v = (i < n) ? cnt[i] : 0;
  int s = v;
#pragma unroll
  for (int d = 1; d < 64; d <<= 1) {
    int t = __shfl_up(s, d);
    if (lane >= d) s += t;
  }
  if (lane == 63) ws[w] = s;
  __syncthreads();
  int add = 0;
  for (int j = 0; j < w; ++j) add += ws[j];
  if (i < n) rstart[i] = s + add - v;
  if (tid == 255) bsum[blockIdx.x] = s + add;
}

__global__ __launch_bounds__(256) void k_scan_small(const int* __restrict__ bsum,
                                                    int* __restrict__ bsumx, int nb) {
  __shared__ int ws[4];
  int tid = threadIdx.x;
  int lane = tid & 63, w = tid >> 6;
  int v = (tid < nb) ? bsum[tid] : 0;
  int s = v;
#pragma unroll
  for (int d = 1; d < 64; d <<= 1) {
    int t = __shfl_up(s, d);
    if (lane >= d) s += t;
  }
  if (lane == 63) ws[w] = s;
  __syncthreads();
  int add = 0;
  for (int j = 0; j < w; ++j) add += ws[j];
  if (tid < nb) bsumx[tid] = s + add - v;
}

__global__ void k_scan_add(int* __restrict__ rstart, int* __restrict__ nxt,
                           const int* __restrict__ bsumx, int n) {
  int i = blockIdx.x * 256 + threadIdx.x;
  if (i < n) {
    int v = rstart[i] + bsumx[blockIdx.x];
    rstart[i] = v;
    nxt[i] = v;
  }
}

__global__ void k_scatter_csr(const int* __restrict__ row, const int* __restrict__ col,
                              const int* __restrict__ etype, const float* __restrict__ ew,
                              int* __restrict__ nxt, int2* __restrict__ epk, int E) {
  int e = blockIdx.x * blockDim.x + threadIdx.x;
  if (e < E) {
    int r = row[e];
    int pos = atomicAdd(&nxt[r], 1);
    epk[pos] = make_int2(col[e] | (etype[e] << 16), __float_as_int(ew[e]));
  }
}

// ---------------- fused main: one wave per row ----------------
// block = 1024 threads = 16 waves = 16 rows. Waves 0-7 also do MFMA/LN/store.

template <bool BF16X>
__global__ __launch_bounds__(1024, 8) void k_main(
    const float* __restrict__ x, const unsigned short* __restrict__ xb,
    const int* __restrict__ rstart, const int* __restrict__ rcnt, int binned,
    const int2* __restrict__ epk, const float* __restrict__ alpha,
    const unsigned short* __restrict__ WbB, const unsigned short* __restrict__ wselfB,
    const float* __restrict__ gamma, const float* __restrict__ beta,
    const float* __restrict__ bias, float* __restrict__ out, int N) {
  __shared__ unsigned short g[NB * 2048];  // 8 basis tiles: 16 rows x 256B, XOR-swizzled
  __shared__ float alds[NT * NB];
  __shared__ float2 stats[16][8];

  int tid = threadIdx.x;
  int lane = tid & 63;
  int wid = tid >> 6;  // local row 0..15
  int l15 = lane & 15, lq = lane >> 4;
  int rbase = blockIdx.x * 16;
  int r = rbase + wid;

  if (tid < NT * NB) alds[tid] = alpha[tid];
  __syncthreads();

  float acc[NB][2];
#pragma unroll
  for (int b = 0; b < NB; ++b) { acc[b][0] = 0.f; acc[b][1] = 0.f; }
  float dsum = 0.f;

  int sb = 0, d = 0;
  if (r < N) {
    d = rcnt[r];
    sb = binned ? r * CAP : rstart[r];
    if (binned && d > CAP) d = CAP;
  }
  int se = sb + d;

  int e = sb;
  for (; e + 2 <= se; e += 2) {
    int2 p0 = epk[e];
    int2 p1 = epk[e + 1];
    float lo0, hi0, lo1, hi1;
    if constexpr (BF16X) {
      unsigned int u0 =
          *(const unsigned int*)(xb + (((size_t)(p0.x & 0xFFFF)) << 7) + (lane << 1));
      unsigned int u1 =
          *(const unsigned int*)(xb + (((size_t)(p1.x & 0xFFFF)) << 7) + (lane << 1));
      lo0 = __uint_as_float(u0 << 16); hi0 = __uint_as_float(u0 & 0xFFFF0000u);
      lo1 = __uint_as_float(u1 << 16); hi1 = __uint_as_float(u1 & 0xFFFF0000u);
    } else {
      float2 v0 = *(const float2*)(x + (((size_t)(p0.x & 0xFFFF)) << 7) + (lane << 1));
      float2 v1 = *(const float2*)(x + (((size_t)(p1.x & 0xFFFF)) << 7) + (lane << 1));
      lo0 = v0.x; hi0 = v0.y; lo1 = v1.x; hi1 = v1.y;
    }
    float w0 = __int_as_float(p0.y), w1 = __int_as_float(p1.y);
    dsum += w0 + w1;
    float4 A00 = *(const float4*)&alds[(p0.x >> 16) * 8];
    float4 A01 = *(const float4*)&alds[(p0.x >> 16) * 8 + 4];
    float4 A10 = *(const float4*)&alds[(p1.x >> 16) * 8];
    float4 A11 = *(const float4*)&alds[(p1.x >> 16) * 8 + 4];
    float a0v[8] = {A00.x, A00.y, A00.z, A00.w, A01.x, A01.y, A01.z, A01.w};
    float a1v[8] = {A10.x, A10.y, A10.z, A10.w, A11.x, A11.y, A11.z, A11.w};
#pragma unroll
    for (int b = 0; b < NB; ++b) {
      float c0 = w0 * a0v[b];
      acc[b][0] += c0 * lo0; acc[b][1] += c0 * hi0;
    }
#pragma unroll
    for (int b = 0; b < NB; ++b) {
      float c1 = w1 * a1v[b];
      acc[b][0] += c1 * lo1; acc[b][1] += c1 * hi1;
    }
  }
  if (e < se) {
    int2 p0 = epk[e];
    float lo0, hi0;
    if constexpr (BF16X) {
      unsigned int u0 =
          *(const unsigned int*)(xb + (((size_t)(p0.x & 0xFFFF)) << 7) + (lane << 1));
      lo0 = __uint_as_float(u0 << 16); hi0 = __uint_as_float(u0 & 0xFFFF0000u);
    } else {
      float2 v0 = *(const float2*)(x + (((size_t)(p0.x & 0xFFFF)) << 7) + (lane << 1));
      lo0 = v0.x; hi0 = v0.y;
    }
    float w0 = __int_as_float(p0.y);
    dsum += w0;
    float4 A00 = *(const float4*)&alds[(p0.x >> 16) * 8];
    float4 A01 = *(const float4*)&alds[(p0.x >> 16) * 8 + 4];
    float a0v[8] = {A00.x, A00.y, A00.z, A00.w, A01.x, A01.y, A01.z, A01.w};
#pragma unroll
    for (int b = 0; b < NB; ++b) {
      float c0 = w0 * a0v[b];
      acc[b][0] += c0 * lo0; acc[b][1] += c0 * hi0;
    }
  }

  // write basis tiles (feats 2*lane, 2*lane+1 at byte 4*lane, XOR bits 4-6 by row&7)
  float rdeg = 1.f / fmaxf(dsum, 1e-12f);
  int wofs = wid * 256 + ((lane << 2) ^ ((wid & 7) << 4));
#pragma unroll
  for (int b = 0; b < NB; ++b)
    *(unsigned int*)((char*)g + b * 4096 + wofs) =
        packbf2(acc[b][0] * rdeg, acc[b][1] * rdeg);
  __syncthreads();

  f32x4 accA = (f32x4)0.f, accS = (f32x4)0.f;
  if (wid < 8) {
    int ct = wid;
#pragma unroll
    for (int b = 0; b < NB; ++b) {
#pragma unroll
      for (int ks = 0; ks < 4; ++ks) {
        short8 av = *(const short8*)((const char*)g + b * 4096 + l15 * 256 +
                                     ((ks * 64 + lq * 16) ^ ((l15 & 7) << 4)));
        short8 bw = *(const short8*)(WbB +
            (size_t)(((b * 8 + ct) * 4 + ks) * 4 + lq) * 128 + l15 * 8);
        accA = __builtin_amdgcn_mfma_f32_16x16x32_bf16(av, bw, accA, 0, 0, 0);
      }
    }
    // self term: A-frags straight from global
    int rs_row = rbase + l15;
#pragma unroll
    for (int ks = 0; ks < 4; ++ks) {
      short8 av;
      if constexpr (BF16X) {
        if (rs_row < N)
          av = *(const short8*)(xb + ((size_t)rs_row << 7) + ks * 32 + lq * 8);
        else
          av = (short8)(short)0;
      } else {
        uint4 q = make_uint4(0u, 0u, 0u, 0u);
        if (rs_row < N) {
          const float* xp = x + ((size_t)rs_row << 7) + ks * 32 + lq * 8;
          float4 v0 = *(const float4*)xp;
          float4 v1 = *(const float4*)(xp + 4);
          q = make_uint4(packbf2(v0.x, v0.y), packbf2(v0.z, v0.w),
                         packbf2(v1.x, v1.y), packbf2(v1.z, v1.w));
        }
        av = *(short8*)&q;
      }
      short8 bw = *(const short8*)(wselfB + (size_t)((ct * 4 + ks) * 4 + lq) * 128 + l15 * 8);
      accS = __builtin_amdgcn_mfma_f32_16x16x32_bf16(av, bw, accS, 0, 0, 0);
    }
    // LN partial stats (reduce over this wave's 16 cols)
#pragma unroll
    for (int reg = 0; reg < 4; ++reg) {
      float v = accA[reg];
      float s1 = v, s2 = v * v;
#pragma unroll
      for (int m = 1; m < 16; m <<= 1) {
        s1 += __shfl_xor(s1, m);
        s2 += __shfl_xor(s2, m);
      }
      if (l15 == 0) stats[lq * 4 + reg][ct] = make_float2(s1, s2);
    }
  }
  __syncthreads();
  if (wid < 8) {
    int ct = wid;
    int c = ct * 16 + l15;
    float ga = gamma[c], be = beta[c], bi = bias[c];
#pragma unroll
    for (int reg = 0; reg < 4; ++reg) {
      int rowl = lq * 4 + reg;
      float S1 = 0.f, S2 = 0.f;
#pragma unroll
      for (int k2 = 0; k2 < 8; ++k2) {
        float2 p = stats[rowl][k2];
        S1 += p.x; S2 += p.y;
      }
      float mu = S1 * (1.f / 128.f);
      float var = S2 * (1.f / 128.f) - mu * mu;
      float rstd = rsqrtf(fmaxf(var, 0.f) + 1e-5f);
      int rg = rbase + rowl;
      if (rg < N)
        out[(size_t)rg * 128 + c] = (accA[reg] - mu) * rstd * ga + be + bi + accS[reg];
    }
  }
}

extern "C" void kernel_launch(void* const* d_in, const int* in_sizes, int n_in,
                              void* d_out, int out_size, void* d_ws, size_t ws_size,
                              hipStream_t stream) {
  const float* x = (const float*)d_in[0];
  const int* ei = (const int*)d_in[1];
  const int* etype = (const int*)d_in[2];
  const float* ew = (const float*)d_in[3];
  const float* weight = (const float*)d_in[4];
  const float* alpha = (const float*)d_in[5];
  const float* bias = (const float*)d_in[6];
  const float* wself = (const float*)d_in[7];
  const float* gamma = (const float*)d_in[8];
  const float* beta = (const float*)d_in[9];
  float* out = (float*)d_out;

  int N = in_sizes[0] / 128;
  int E = in_sizes[2];
  const int* row = ei;
  const int* col = ei + E;

  auto au = [](size_t v) { return (v + 255) & ~(size_t)255; };
  size_t sz_xb = (size_t)N * 128 * 2;
  size_t sz_WbB = (size_t)NB * 128 * 128 * 2;
  size_t sz_wsB = (size_t)128 * 128 * 2;

  // binned layout
  size_t b_rcnt = 0;
  size_t b_epk = au((size_t)N * 4);
  size_t b_xb = b_epk + au((size_t)N * CAP * 8);
  size_t b_WbB = b_xb + au(sz_xb);
  size_t b_wsB = b_WbB + au(sz_WbB);
  size_t need_binned = b_wsB + au(sz_wsB);

  // csr layout
  size_t c_cnt = 0;
  size_t c_rstart = au((size_t)N * 4);
  size_t c_nxt = c_rstart + au((size_t)N * 4);
  size_t c_bsum = c_nxt + au((size_t)N * 4);
  size_t c_bsumx = c_bsum + 1024;
  size_t c_epk = c_bsumx + 1024;
  size_t c_xb = c_epk + au((size_t)E * 8);
  size_t c_WbB_x = c_xb + au(sz_xb);
  size_t need_csr_xb = c_WbB_x + au(sz_WbB) + au(sz_wsB);
  size_t c_WbB_nox = c_xb;  // no xb
  size_t need_csr_nox = c_WbB_nox + au(sz_WbB) + au(sz_wsB);

  char* ws = (char*)d_ws;
  int eb = (E + 255) / 256;
  int nb = (N + 255) / 256;
  int mb = (N + 15) / 16;

  if (ws_size >= need_binned) {
    int* rcnt = (int*)(ws + b_rcnt);
    int2* epk = (int2*)(ws + b_epk);
    unsigned short* xb = (unsigned short*)(ws + b_xb);
    unsigned short* WbB = (unsigned short*)(ws + b_WbB);
    unsigned short* wsB = (unsigned short*)(ws + b_wsB);
    hipMemsetAsync(rcnt, 0, (size_t)N * 4, stream);
    k_scatter_bin<<<eb, 256, 0, stream>>>(row, col, etype, ew, rcnt, epk, E);
    k_xprep<<<(N * 16 + 255) / 256, 256, 0, stream>>>(x, xb, N * 16);
    k_wprep<<<(NB * 128 * 128 + 128 * 128 + 255) / 256, 256, 0, stream>>>(
        weight, wself, WbB, wsB);
    k_main<true><<<mb, 1024, 0, stream>>>(x, xb, rcnt, rcnt, 1, epk, alpha, WbB, wsB,
                                          gamma, beta, bias, out, N);
  } else {
    bool have_xb = ws_size >= need_csr_xb;
    int* cnt = (int*)(ws + c_cnt);
    int* rstart = (int*)(ws + c_rstart);
    int* nxt = (int*)(ws + c_nxt);
    int* bsum = (int*)(ws + c_bsum);
    int* bsumx = (int*)(ws + c_bsumx);
    int2* epk = (int2*)(ws + c_epk);
    unsigned short* xb = (unsigned short*)(ws + c_xb);
    unsigned short* WbB = (unsigned short*)(ws + (have_xb ? c_WbB_x : c_WbB_nox));
    unsigned short* wsB = WbB + NB * 128 * 128;
    hipMemsetAsync(cnt, 0, (size_t)N * 4, stream);
    k_count<<<eb, 256, 0, stream>>>(row, cnt, E);
    k_scan_local<<<nb, 256, 0, stream>>>(cnt, rstart, bsum, N);
    k_scan_small<<<1, 256, 0, stream>>>(bsum, bsumx, nb);
    k_scan_add<<<nb, 256, 0, stream>>>(rstart, nxt, bsumx, N);
    k_scatter_csr<<<eb, 256, 0, stream>>>(row, col, etype, ew, nxt, epk, E);
    if (have_xb) k_xprep<<<(N * 16 + 255) / 256, 256, 0, stream>>>(x, xb, N * 16);
    k_wprep<<<(NB * 128 * 128 + 128 * 128 + 255) / 256, 256, 0, stream>>>(
        weight, wself, WbB, wsB);
    if (have_xb)
      k_main<true><<<mb, 1024, 0, stream>>>(x, xb, rstart, cnt, 0, epk, alpha, WbB,
                                            wsB, gamma, beta, bias, out, N);
    else
      k_main<false><<<mb, 1024, 0, stream>>>(x, nullptr, rstart, cnt, 0, epk, alpha,
                                             WbB, wsB, gamma, beta, bias, out, N);
  }
}